// Round 7
// baseline (498.295 us; speedup 1.0000x reference)
//
#include <hip/hip_runtime.h>
#include <stdint.h>

typedef __attribute__((ext_vector_type(8))) short short8;
typedef __attribute__((ext_vector_type(8))) unsigned short ushort8;
typedef __attribute__((ext_vector_type(4))) unsigned short ushort4v;
typedef __attribute__((ext_vector_type(4))) float float4v;
typedef _Float16 half4v __attribute__((ext_vector_type(4)));

#define D_MODEL 1024
#define NHEAD 16
#define DIM_HEAD 64
#define BATCH 2
#define SEQ 2048
#define BH (BATCH*NHEAD)
#define MROWS (BATCH*SEQ)   // 4096
#define MK ((size_t)MROWS * D_MODEL)   // 4194304 elems per activation tensor
#define NSPLIT 4

__device__ __forceinline__ unsigned short f2bf(float f) {
  union { float f; unsigned u; } v; v.f = f;
  unsigned r = v.u + 0x7fffu + ((v.u >> 16) & 1u);   // RNE
  return (unsigned short)(r >> 16);
}
__device__ __forceinline__ unsigned short f2bf_fast(float f) {
  union { float f; unsigned u; } v; v.f = f;
  return (unsigned short)((v.u + 0x8000u) >> 16);
}
// pack bf16(a) | bf16(b)<<16 via v_perm
__device__ __forceinline__ unsigned pk2bf(float a, float b) {
  union { float f; unsigned u; } x, y; x.f = a; y.f = b;
  return __builtin_amdgcn_perm(y.u + 0x8000u, x.u + 0x8000u, 0x07060302u);
}

// async global->LDS, 16B per lane; lds base must be wave-uniform
__device__ __forceinline__ void gld16(const unsigned short* g, unsigned short* l) {
  __builtin_amdgcn_global_load_lds(
      (const __attribute__((address_space(1))) unsigned int*)g,
      (__attribute__((address_space(3))) unsigned int*)l, 16, 0, 0);
}

// ---- fused weight transpose+cast: WT[z][n][k] = bf16(W[z][k][n] * scale) ---
__global__ __launch_bounds__(256) void wtrans_kernel(const float* __restrict__ Wq,
    const float* __restrict__ Wk, const float* __restrict__ Wv,
    const float* __restrict__ Wo, unsigned short* __restrict__ WT0) {
  __shared__ float tile[32][33];
  const int z = blockIdx.z;
  const float* W = (z == 0) ? Wq : (z == 1) ? Wk : (z == 2) ? Wv : Wo;
  const float scale = (z == 0) ? 0.125f : 1.0f;   // fold SCALE into Wq
  unsigned short* WT = WT0 + ((size_t)z << 20);
  int bn = blockIdx.x * 32;
  int bk = blockIdx.y * 32;
  int tx = threadIdx.x & 31, ty = threadIdx.x >> 5;
#pragma unroll
  for (int i = 0; i < 4; i++)
    tile[ty + i*8][tx] = W[(size_t)(bk + ty + i*8) * D_MODEL + bn + tx];
  __syncthreads();
#pragma unroll
  for (int i = 0; i < 4; i++)
    WT[(size_t)(bn + ty + i*8) * D_MODEL + bk + tx] = f2bf(tile[tx][ty + i*8] * scale);
}

// ---- cast q/k/v fp32 -> bf16, y picks tensor -------------------------------
__global__ __launch_bounds__(256) void cast_kernel(const float* __restrict__ q,
    const float* __restrict__ k, const float* __restrict__ v,
    unsigned short* __restrict__ out) {
  const float* src = (blockIdx.y == 0) ? q : (blockIdx.y == 1) ? k : v;
  unsigned short* dst = out + (size_t)blockIdx.y * MK;
  size_t idx = ((size_t)blockIdx.x * 256 + threadIdx.x) * 8;
  float4v a = *(const float4v*)(src + idx);
  float4v b = *(const float4v*)(src + idx + 4);
  ushort8 o;
  o[0] = f2bf(a[0]); o[1] = f2bf(a[1]); o[2] = f2bf(a[2]); o[3] = f2bf(a[3]);
  o[4] = f2bf(b[0]); o[5] = f2bf(b[1]); o[6] = f2bf(b[2]); o[7] = f2bf(b[3]);
  *(ushort8*)(dst + idx) = o;
}

// ---- V transpose: Vh [b,h,n,d] -> panelized VT2 [b,h,n/64, d, 64] ----------
__global__ __launch_bounds__(256) void vtrans_kernel(const unsigned short* __restrict__ Vh,
                                                     unsigned short* __restrict__ VT) {
  __shared__ unsigned short tile[64][72];
  const int bh = blockIdx.x;
  const int n0 = blockIdx.y * 64;
  const int t = threadIdx.x;
#pragma unroll
  for (int p = 0; p < 2; p++) {
    int g = p*256 + t; int row = g >> 3, c = g & 7;
    *(ushort8*)&tile[row][c*8] =
      *(const ushort8*)(Vh + ((size_t)(bh*SEQ + n0 + row))*DIM_HEAD + c*8);
  }
  __syncthreads();
  int d = t >> 2, kc = (t & 3) * 16;
  ushort8 o0, o1;
#pragma unroll
  for (int j = 0; j < 8; j++) { o0[j] = tile[kc + j][d]; o1[j] = tile[kc + 8 + j][d]; }
  unsigned short* dst = VT + (((size_t)(bh*(SEQ/64) + blockIdx.y))*DIM_HEAD + d)*64 + kc;
  *(ushort8*)dst = o0;
  *(ushort8*)(dst + 8) = o1;
}

// ---- fused QKV projection (m97-style: unpadded LDS + gld16) ----------------
// Output is HEAD-MAJOR: Yh[b,h,n,d]
__global__ __launch_bounds__(256, 3) void proj_kernel(const unsigned short* __restrict__ Xbf,
    const unsigned short* __restrict__ WT0, unsigned short* __restrict__ Y0) {
  __shared__ unsigned short Al[128*64];
  __shared__ unsigned short Bl[128*64];
  const int z = blockIdx.z;
  const unsigned short* A  = Xbf + (size_t)z * MK;
  const unsigned short* BT = WT0 + ((size_t)z << 20);
  unsigned short* Y = Y0 + (size_t)z * MK;
  const int m0 = blockIdx.x * 128, n0 = blockIdx.y * 128;
  const int t = threadIdx.x;
  const int lane = t & 63, w = t >> 6, quad = lane >> 4, lid = lane & 15;
  const int wm = w & 1, wn = w >> 1;
  const int r8 = lane >> 3, c8 = (lane & 7) * 8;

  float4v acc[4][4];
#pragma unroll
  for (int i = 0; i < 4; i++)
#pragma unroll
    for (int j = 0; j < 4; j++) acc[i][j] = (float4v)0.0f;

  for (int k0 = 0; k0 < D_MODEL; k0 += 64) {
#pragma unroll
    for (int p = 0; p < 4; p++) {
      int seg = w*4 + p;
      gld16(A  + (size_t)(m0 + seg*8 + r8) * D_MODEL + k0 + c8, &Al[seg*8*64]);
      gld16(BT + (size_t)(n0 + seg*8 + r8) * D_MODEL + k0 + c8, &Bl[seg*8*64]);
    }
    __syncthreads();
#pragma unroll
    for (int kst = 0; kst < 2; kst++) {
      short8 af[4], bfr[4];
#pragma unroll
      for (int i = 0; i < 4; i++)
        af[i] = *(const short8*)&Al[(wm*64 + i*16 + lid)*64 + kst*32 + quad*8];
#pragma unroll
      for (int j = 0; j < 4; j++)
        bfr[j] = *(const short8*)&Bl[(wn*64 + j*16 + lid)*64 + kst*32 + quad*8];
#pragma unroll
      for (int i = 0; i < 4; i++)
#pragma unroll
        for (int j = 0; j < 4; j++)
          acc[i][j] = __builtin_amdgcn_mfma_f32_16x16x32_bf16(af[i], bfr[j], acc[i][j], 0, 0, 0);
    }
    __syncthreads();
  }
#pragma unroll
  for (int i = 0; i < 4; i++)
#pragma unroll
    for (int j = 0; j < 4; j++)
#pragma unroll
      for (int r = 0; r < 4; r++) {
        int row = m0 + wm*64 + i*16 + quad*4 + r;
        int col = n0 + wn*64 + j*16 + lid;
        int b = row >> 11, n = row & (SEQ - 1);
        int h = col >> 6,  d = col & 63;
        Y[(((size_t)(b*NHEAD + h))*SEQ + n)*DIM_HEAD + d] = f2bf_fast(acc[i][j][r]);
      }
}

// ---- output projection: out(fp32) = A(bf16) @ Wo + bo ----------------------
__global__ __launch_bounds__(256, 3) void outproj_kernel(const unsigned short* __restrict__ A,
    const unsigned short* __restrict__ WT, const float* __restrict__ bias,
    float* __restrict__ out) {
  __shared__ unsigned short Al[64*64];
  __shared__ unsigned short Bl[128*64];
  const int m0 = blockIdx.x * 64, n0 = blockIdx.y * 128;
  const int t = threadIdx.x;
  const int lane = t & 63, w = t >> 6, quad = lane >> 4, lid = lane & 15;
  const int wm = w & 1, wn = w >> 1;
  const int r8 = lane >> 3, c8 = (lane & 7) * 8;

  float4v acc[2][4];
#pragma unroll
  for (int i = 0; i < 2; i++)
#pragma unroll
    for (int j = 0; j < 4; j++) acc[i][j] = (float4v)0.0f;

  for (int k0 = 0; k0 < D_MODEL; k0 += 64) {
#pragma unroll
    for (int p = 0; p < 2; p++) {
      int seg = w*2 + p;
      gld16(A + (size_t)(m0 + seg*8 + r8) * D_MODEL + k0 + c8, &Al[seg*8*64]);
    }
#pragma unroll
    for (int p = 0; p < 4; p++) {
      int seg = w*4 + p;
      gld16(WT + (size_t)(n0 + seg*8 + r8) * D_MODEL + k0 + c8, &Bl[seg*8*64]);
    }
    __syncthreads();
#pragma unroll
    for (int kst = 0; kst < 2; kst++) {
      short8 af[2], bfr[4];
#pragma unroll
      for (int i = 0; i < 2; i++)
        af[i] = *(const short8*)&Al[(wm*32 + i*16 + lid)*64 + kst*32 + quad*8];
#pragma unroll
      for (int j = 0; j < 4; j++)
        bfr[j] = *(const short8*)&Bl[(wn*64 + j*16 + lid)*64 + kst*32 + quad*8];
#pragma unroll
      for (int i = 0; i < 2; i++)
#pragma unroll
        for (int j = 0; j < 4; j++)
          acc[i][j] = __builtin_amdgcn_mfma_f32_16x16x32_bf16(af[i], bfr[j], acc[i][j], 0, 0, 0);
    }
    __syncthreads();
  }
#pragma unroll
  for (int i = 0; i < 2; i++)
#pragma unroll
    for (int j = 0; j < 4; j++)
#pragma unroll
      for (int r = 0; r < 4; r++) {
        int row = m0 + wm*32 + i*16 + quad*4 + r;
        int col = n0 + wn*64 + j*16 + lid;
        out[(size_t)row * D_MODEL + col] = acc[i][j][r] + bias[col];
      }
}

// ---- barrier-free flash attention, split-K x4 for TLP ----------------------
// Qh,Kh head-major [b,h,n,d]; VT2 panelized [b,h,n/64,d,64].
// S^T = K Q^T, O^T = V^T P^T. Only P transits LDS (per-wave, 2 alternating
// buffers, no __syncthreads). Grid 1024 = 4 blocks/CU = 4 waves/SIMD.
#define PSTR 68

__global__ __launch_bounds__(256, 4) void flash_kernel(const unsigned short* __restrict__ Q,
    const unsigned short* __restrict__ K, const unsigned short* __restrict__ VT,
    _Float16* __restrict__ Op0, float* __restrict__ lpart) {
  __shared__ unsigned short Pl[4][2][16*PSTR];   // [wave][buf] = 17408 B

  // 1024 blocks; cluster one bh's 32 blocks onto one XCD (flat % 8 = XCD)
  const int flat = blockIdx.x;
  const int bh  = (flat & 7) * 4 + ((flat >> 3) & 3);
  const int qz  = flat >> 5;          // 0..31
  const int qb  = qz & 7, z = qz >> 3;   // 8 query blocks x 4 splits
  const int t = threadIdx.x;
  const int lane = t & 63, w = t >> 6, quad = lane >> 4, lid = lane & 15;
  const int q0 = qb * 256 + w * 64;
  const int kbeg = z * (SEQ/NSPLIT);
  _Float16* Op = Op0 + (size_t)z * BH * SEQ * DIM_HEAD;
  float* lp = lpart + (size_t)z * BH * SEQ;

  // Q fragments (B-frag): lane lid = query row, contiguous 2KB per load
  short8 qf[4][2];
#pragma unroll
  for (int st = 0; st < 4; st++)
#pragma unroll
    for (int kst = 0; kst < 2; kst++)
      qf[st][kst] = *(const short8*)(Q +
        ((size_t)(bh*SEQ + q0 + st*16 + lid))*DIM_HEAD + kst*32 + quad*8);

  float4v o[4][4];
#pragma unroll
  for (int st = 0; st < 4; st++)
#pragma unroll
    for (int i = 0; i < 4; i++) o[st][i] = (float4v)0.0f;
  float ps[4] = {0.0f, 0.0f, 0.0f, 0.0f};

  for (int kb = kbeg; kb < kbeg + SEQ/NSPLIT; kb += 64) {
    short8 kf[2][4], vf[2][4];
    // K fragments (A-frag): lane lid = key row, contiguous 2KB per load
#pragma unroll
    for (int kst = 0; kst < 2; kst++)
#pragma unroll
      for (int mb = 0; mb < 4; mb++)
        kf[kst][mb] = *(const short8*)(K +
          ((size_t)(bh*SEQ + kb + mb*16 + lid))*DIM_HEAD + kst*32 + quad*8);
    // V^T fragments (A-frag): panel (bh, kb/64), lane lid = d row, contiguous
    const unsigned short* Vp = VT + ((size_t)(bh*(SEQ/64) + (kb >> 6)))*DIM_HEAD*64;
#pragma unroll
    for (int kst = 0; kst < 2; kst++)
#pragma unroll
      for (int i = 0; i < 4; i++)
        vf[kst][i] = *(const short8*)(Vp + (size_t)(i*16 + lid)*64 + kst*32 + quad*8);

#pragma unroll
    for (int st = 0; st < 4; st++) {
      // S^T = K Q^T : C col=lid=query, row=key mb*16+quad*4+r
      float4v s[4];
#pragma unroll
      for (int mb = 0; mb < 4; mb++) s[mb] = (float4v)0.0f;
#pragma unroll
      for (int kst = 0; kst < 2; kst++)
#pragma unroll
        for (int mb = 0; mb < 4; mb++)
          s[mb] = __builtin_amdgcn_mfma_f32_16x16x32_bf16(kf[kst][mb], qf[st][kst], s[mb], 0, 0, 0);

      unsigned short* Ptw = &Pl[w][st & 1][0];
#pragma unroll
      for (int mb = 0; mb < 4; mb++) {
        float e0 = __expf(s[mb][0]);
        float e1 = __expf(s[mb][1]);
        float e2 = __expf(s[mb][2]);
        float e3 = __expf(s[mb][3]);
        ps[st] += (e0 + e1) + (e2 + e3);
        uint2 pk; pk.x = pk2bf(e0, e1); pk.y = pk2bf(e2, e3);
        *(uint2*)&Ptw[lid*PSTR + mb*16 + quad*4] = pk;
      }
      short8 pf0 = *(const short8*)&Ptw[lid*PSTR + quad*8];
      short8 pf1 = *(const short8*)&Ptw[lid*PSTR + 32 + quad*8];
#pragma unroll
      for (int i = 0; i < 4; i++) {
        o[st][i] = __builtin_amdgcn_mfma_f32_16x16x32_bf16(vf[0][i], pf0, o[st][i], 0, 0, 0);
        o[st][i] = __builtin_amdgcn_mfma_f32_16x16x32_bf16(vf[1][i], pf1, o[st][i], 0, 0, 0);
      }
    }
  }

  // epilogue: l partial (sum over quads) + fp16 O^T partial
#pragma unroll
  for (int st = 0; st < 4; st++) {
    float v = ps[st];
    v += __shfl_xor(v, 16); v += __shfl_xor(v, 32);
    int q = q0 + st*16 + lid;
    if (quad == 0) lp[(size_t)bh*SEQ + q] = v;
#pragma unroll
    for (int i = 0; i < 4; i++) {
      half4v hv;
#pragma unroll
      for (int r = 0; r < 4; r++) hv[r] = (_Float16)o[st][i][r];
      *(half4v*)(Op + ((size_t)bh*SEQ + q)*64 + i*16 + quad*4) = hv;
    }
  }
}

// ---- combine 4 splits: Ob = bf16(Sum O_z / Sum l_z), layout [b,q,h,d] ------
__global__ __launch_bounds__(256) void norm_kernel(const _Float16* __restrict__ Op,
    const float* __restrict__ lpart, unsigned short* __restrict__ Ob) {
  int g = blockIdx.x * 256 + threadIdx.x;
  int d4 = g & 15, h = (g >> 4) & 15, q = (g >> 8) & (SEQ - 1), b = g >> 19;
  int bh = b * NHEAD + h;
  size_t obase = ((size_t)bh * SEQ + q) * 64 + d4 * 4;
  const size_t zstride = (size_t)BH * SEQ * DIM_HEAD;
  float f0 = 0.f, f1 = 0.f, f2 = 0.f, f3 = 0.f, l = 0.f;
#pragma unroll
  for (int z = 0; z < NSPLIT; z++) {
    half4v a = *(const half4v*)(Op + (size_t)z * zstride + obase);
    f0 += (float)a[0]; f1 += (float)a[1]; f2 += (float)a[2]; f3 += (float)a[3];
    l += lpart[(size_t)z * BH * SEQ + (size_t)bh * SEQ + q];
  }
  float inv = 1.0f / l;
  f0 *= inv; f1 *= inv; f2 *= inv; f3 *= inv;
  uint2 pk; pk.x = pk2bf(f0, f1); pk.y = pk2bf(f2, f3);
  *(uint2*)&Ob[(((size_t)(b*SEQ + q))*NHEAD + h)*64 + d4*4] = pk;
}

extern "C" void kernel_launch(void* const* d_in, const int* in_sizes, int n_in,
                              void* d_out, int out_size, void* d_ws, size_t ws_size,
                              hipStream_t stream) {
  const float* query = (const float*)d_in[0];
  const float* key_  = (const float*)d_in[1];
  const float* value = (const float*)d_in[2];
  const float* Wq = (const float*)d_in[3];
  const float* Wk = (const float*)d_in[4];
  const float* Wv = (const float*)d_in[5];
  const float* Wo = (const float*)d_in[6];
  const float* bo = (const float*)d_in[7];
  float* out = (float*)d_out;

  char* ws = (char*)d_ws;
  unsigned short* WT0 = (unsigned short*)(ws);                  // 4 x 2MB (q,k,v,o)
  unsigned short* Xbf = (unsigned short*)(ws + (8ll  << 20));   // 3 x 8MB (q,k,v)
  unsigned short* VT  = (unsigned short*)(ws + (8ll  << 20));   // reuse Xbf[q] (dead post-proj)
  unsigned short* Ob  = (unsigned short*)(ws + (16ll << 20));   // reuse Xbf[k] (dead post-proj)
  unsigned short* Qb  = (unsigned short*)(ws + (32ll << 20));   // head-major [b,h,n,d]
  unsigned short* Kb  = (unsigned short*)(ws + (40ll << 20));   // head-major
  unsigned short* Vb  = (unsigned short*)(ws + (48ll << 20));   // head-major
  _Float16*       Op  = (_Float16*)     (ws + (56ll << 20));    // 4 x 8MB split partials
  float*          lp  = (float*)        (ws + (88ll << 20));    // 1MB

  dim3 tb(256);
  dim3 tg(32, 32, 4);
  hipLaunchKernelGGL(wtrans_kernel, tg, tb, 0, stream, Wq, Wk, Wv, Wo, WT0);

  dim3 cg(MK / (256*8), 3);
  hipLaunchKernelGGL(cast_kernel, cg, tb, 0, stream, query, key_, value, Xbf);

  dim3 pg(MROWS/128, D_MODEL/128, 3);   // 768 blocks
  hipLaunchKernelGGL(proj_kernel, pg, tb, 0, stream, Xbf, WT0, Qb);

  dim3 vg(BH, SEQ/64);
  hipLaunchKernelGGL(vtrans_kernel, vg, tb, 0, stream, Vb, VT);

  dim3 fg(1024);                        // barrier-free flash, split-K x4
  hipLaunchKernelGGL(flash_kernel, fg, tb, 0, stream, Qb, Kb, VT, Op, lp);

  dim3 ng((MROWS * NHEAD * DIM_HEAD / 4) / 256);   // 2048 blocks
  hipLaunchKernelGGL(norm_kernel, ng, tb, 0, stream, Op, lp, Ob);

  dim3 og(MROWS/64, D_MODEL/128);       // 512 blocks
  hipLaunchKernelGGL(outproj_kernel, og, tb, 0, stream, Ob, WT0 + (3ll << 20), bo, out);
}

// Round 8
// 239.068 us; speedup vs baseline: 2.0843x; 2.0843x over previous
//
#include <hip/hip_runtime.h>
#include <stdint.h>

typedef __attribute__((ext_vector_type(8))) short short8;
typedef __attribute__((ext_vector_type(8))) unsigned short ushort8;
typedef __attribute__((ext_vector_type(4))) float float4v;
typedef _Float16 half4v __attribute__((ext_vector_type(4)));

#define D_MODEL 1024
#define NHEAD 16
#define DIM_HEAD 64
#define BATCH 2
#define SEQ 2048
#define BH (BATCH*NHEAD)
#define MROWS (BATCH*SEQ)   // 4096
#define MK ((size_t)MROWS * D_MODEL)
#define NSPLIT 2

__device__ __forceinline__ unsigned short f2bf(float f) {
  union { float f; unsigned u; } v; v.f = f;
  unsigned r = v.u + 0x7fffu + ((v.u >> 16) & 1u);   // RNE
  return (unsigned short)(r >> 16);
}
__device__ __forceinline__ unsigned short f2bf_fast(float f) {
  union { float f; unsigned u; } v; v.f = f;
  return (unsigned short)((v.u + 0x8000u) >> 16);
}
__device__ __forceinline__ unsigned pk2bf(float a, float b) {
  union { float f; unsigned u; } x, y; x.f = a; y.f = b;
  return __builtin_amdgcn_perm(y.u + 0x8000u, x.u + 0x8000u, 0x07060302u);
}
__device__ __forceinline__ void gld16(const unsigned short* g, unsigned short* l) {
  __builtin_amdgcn_global_load_lds(
      (const __attribute__((address_space(1))) unsigned int*)g,
      (__attribute__((address_space(3))) unsigned int*)l, 16, 0, 0);
}

// ---- fused weight transpose+cast: WT[z][n][k] = bf16(W[z][k][n] * scale) ---
__global__ __launch_bounds__(256) void wtrans_kernel(const float* __restrict__ Wq,
    const float* __restrict__ Wk, const float* __restrict__ Wv,
    const float* __restrict__ Wo, unsigned short* __restrict__ WT0) {
  __shared__ float tile[32][33];
  const int z = blockIdx.z;
  const float* W = (z == 0) ? Wq : (z == 1) ? Wk : (z == 2) ? Wv : Wo;
  const float scale = (z == 0) ? 0.125f : 1.0f;
  unsigned short* WT = WT0 + ((size_t)z << 20);
  int bn = blockIdx.x * 32;
  int bk = blockIdx.y * 32;
  int tx = threadIdx.x & 31, ty = threadIdx.x >> 5;
#pragma unroll
  for (int i = 0; i < 4; i++)
    tile[ty + i*8][tx] = W[(size_t)(bk + ty + i*8) * D_MODEL + bn + tx];
  __syncthreads();
#pragma unroll
  for (int i = 0; i < 4; i++)
    WT[(size_t)(bn + ty + i*8) * D_MODEL + bk + tx] = f2bf(tile[tx][ty + i*8] * scale);
}

// ---- cast q/k/v fp32 -> bf16 -----------------------------------------------
__global__ __launch_bounds__(256) void cast_kernel(const float* __restrict__ q,
    const float* __restrict__ k, const float* __restrict__ v,
    unsigned short* __restrict__ out) {
  const float* src = (blockIdx.y == 0) ? q : (blockIdx.y == 1) ? k : v;
  unsigned short* dst = out + (size_t)blockIdx.y * MK;
  size_t idx = ((size_t)blockIdx.x * 256 + threadIdx.x) * 8;
  float4v a = *(const float4v*)(src + idx);
  float4v b = *(const float4v*)(src + idx + 4);
  ushort8 o;
  o[0] = f2bf(a[0]); o[1] = f2bf(a[1]); o[2] = f2bf(a[2]); o[3] = f2bf(a[3]);
  o[4] = f2bf(b[0]); o[5] = f2bf(b[1]); o[6] = f2bf(b[2]); o[7] = f2bf(b[3]);
  *(ushort8*)(dst + idx) = o;
}

// ---- V transpose: Vh [b,h,n,d] -> panelized VT [b,h,n/64, d, 64] -----------
__global__ __launch_bounds__(256) void vtrans_kernel(const unsigned short* __restrict__ Vh,
                                                     unsigned short* __restrict__ VT) {
  __shared__ unsigned short tile[64][72];
  const int bh = blockIdx.x;
  const int n0 = blockIdx.y * 64;
  const int t = threadIdx.x;
#pragma unroll
  for (int p = 0; p < 2; p++) {
    int g = p*256 + t; int row = g >> 3, c = g & 7;
    *(ushort8*)&tile[row][c*8] =
      *(const ushort8*)(Vh + ((size_t)(bh*SEQ + n0 + row))*DIM_HEAD + c*8);
  }
  __syncthreads();
  int d = t >> 2, kc = (t & 3) * 16;
  ushort8 o0, o1;
#pragma unroll
  for (int j = 0; j < 8; j++) { o0[j] = tile[kc + j][d]; o1[j] = tile[kc + 8 + j][d]; }
  unsigned short* dst = VT + (((size_t)(bh*(SEQ/64) + blockIdx.y))*DIM_HEAD + d)*64 + kc;
  *(ushort8*)dst = o0;
  *(ushort8*)(dst + 8) = o1;
}

// ---- fused QKV projection (m97-style), head-major output Yh[b,h,n,d] -------
__global__ __launch_bounds__(256, 3) void proj_kernel(const unsigned short* __restrict__ Xbf,
    const unsigned short* __restrict__ WT0, unsigned short* __restrict__ Y0) {
  __shared__ unsigned short Al[128*64];
  __shared__ unsigned short Bl[128*64];
  const int z = blockIdx.z;
  const unsigned short* A  = Xbf + (size_t)z * MK;
  const unsigned short* BT = WT0 + ((size_t)z << 20);
  unsigned short* Y = Y0 + (size_t)z * MK;
  const int m0 = blockIdx.x * 128, n0 = blockIdx.y * 128;
  const int t = threadIdx.x;
  const int lane = t & 63, w = t >> 6, quad = lane >> 4, lid = lane & 15;
  const int wm = w & 1, wn = w >> 1;
  const int r8 = lane >> 3, c8 = (lane & 7) * 8;

  float4v acc[4][4];
#pragma unroll
  for (int i = 0; i < 4; i++)
#pragma unroll
    for (int j = 0; j < 4; j++) acc[i][j] = (float4v)0.0f;

  for (int k0 = 0; k0 < D_MODEL; k0 += 64) {
#pragma unroll
    for (int p = 0; p < 4; p++) {
      int seg = w*4 + p;
      gld16(A  + (size_t)(m0 + seg*8 + r8) * D_MODEL + k0 + c8, &Al[seg*8*64]);
      gld16(BT + (size_t)(n0 + seg*8 + r8) * D_MODEL + k0 + c8, &Bl[seg*8*64]);
    }
    __syncthreads();
#pragma unroll
    for (int kst = 0; kst < 2; kst++) {
      short8 af[4], bfr[4];
#pragma unroll
      for (int i = 0; i < 4; i++)
        af[i] = *(const short8*)&Al[(wm*64 + i*16 + lid)*64 + kst*32 + quad*8];
#pragma unroll
      for (int j = 0; j < 4; j++)
        bfr[j] = *(const short8*)&Bl[(wn*64 + j*16 + lid)*64 + kst*32 + quad*8];
#pragma unroll
      for (int i = 0; i < 4; i++)
#pragma unroll
        for (int j = 0; j < 4; j++)
          acc[i][j] = __builtin_amdgcn_mfma_f32_16x16x32_bf16(af[i], bfr[j], acc[i][j], 0, 0, 0);
    }
    __syncthreads();
  }
#pragma unroll
  for (int i = 0; i < 4; i++)
#pragma unroll
    for (int j = 0; j < 4; j++)
#pragma unroll
      for (int r = 0; r < 4; r++) {
        int row = m0 + wm*64 + i*16 + quad*4 + r;
        int col = n0 + wn*64 + j*16 + lid;
        int b = row >> 11, n = row & (SEQ - 1);
        int h = col >> 6,  d = col & 63;
        Y[(((size_t)(b*NHEAD + h))*SEQ + n)*DIM_HEAD + d] = f2bf_fast(acc[i][j][r]);
      }
}

// ---- output projection: out(fp32) = A(bf16) @ Wo + bo ----------------------
__global__ __launch_bounds__(256, 3) void outproj_kernel(const unsigned short* __restrict__ A,
    const unsigned short* __restrict__ WT, const float* __restrict__ bias,
    float* __restrict__ out) {
  __shared__ unsigned short Al[64*64];
  __shared__ unsigned short Bl[128*64];
  const int m0 = blockIdx.x * 64, n0 = blockIdx.y * 128;
  const int t = threadIdx.x;
  const int lane = t & 63, w = t >> 6, quad = lane >> 4, lid = lane & 15;
  const int wm = w & 1, wn = w >> 1;
  const int r8 = lane >> 3, c8 = (lane & 7) * 8;

  float4v acc[2][4];
#pragma unroll
  for (int i = 0; i < 2; i++)
#pragma unroll
    for (int j = 0; j < 4; j++) acc[i][j] = (float4v)0.0f;

  for (int k0 = 0; k0 < D_MODEL; k0 += 64) {
#pragma unroll
    for (int p = 0; p < 2; p++) {
      int seg = w*2 + p;
      gld16(A + (size_t)(m0 + seg*8 + r8) * D_MODEL + k0 + c8, &Al[seg*8*64]);
    }
#pragma unroll
    for (int p = 0; p < 4; p++) {
      int seg = w*4 + p;
      gld16(WT + (size_t)(n0 + seg*8 + r8) * D_MODEL + k0 + c8, &Bl[seg*8*64]);
    }
    __syncthreads();
#pragma unroll
    for (int kst = 0; kst < 2; kst++) {
      short8 af[2], bfr[4];
#pragma unroll
      for (int i = 0; i < 2; i++)
        af[i] = *(const short8*)&Al[(wm*32 + i*16 + lid)*64 + kst*32 + quad*8];
#pragma unroll
      for (int j = 0; j < 4; j++)
        bfr[j] = *(const short8*)&Bl[(wn*64 + j*16 + lid)*64 + kst*32 + quad*8];
#pragma unroll
      for (int i = 0; i < 2; i++)
#pragma unroll
        for (int j = 0; j < 4; j++)
          acc[i][j] = __builtin_amdgcn_mfma_f32_16x16x32_bf16(af[i], bfr[j], acc[i][j], 0, 0, 0);
    }
    __syncthreads();
  }
#pragma unroll
  for (int i = 0; i < 2; i++)
#pragma unroll
    for (int j = 0; j < 4; j++)
#pragma unroll
      for (int r = 0; r < 4; r++) {
        int row = m0 + wm*32 + i*16 + quad*4 + r;
        int col = n0 + wn*64 + j*16 + lid;
        out[(size_t)row * D_MODEL + col] = acc[i][j][r] + bias[col];
      }
}

// ---- flash attention: LDS-shared dbuf K/V (gld16) + S^T math ---------------
// Qh,Kh head-major [b,h,n,d]; VT panelized [b,h,n/64,d,64].
// Block = 4 waves x 64 queries = 256 q; split-K x2; ONE barrier per iter:
//   sync (DMA-for-cur drained + prev-buf readers done) -> stage next -> compute cur
// K/V fragments read from LDS (shared across 4 waves: 8x less L2 than R6).
// P transits per-wave LDS (packed b64 stores, conflict-free, PSTR=68).
#define PSTR 68

__global__ __launch_bounds__(256, 2) void flash_kernel(const unsigned short* __restrict__ Q,
    const unsigned short* __restrict__ K, const unsigned short* __restrict__ VT,
    _Float16* __restrict__ Op0, float* __restrict__ lpart) {
  __shared__ unsigned short Kl[2][64*64];        // 2 x 8 KB
  __shared__ unsigned short Vl[2][64*64];        // 2 x 8 KB
  __shared__ unsigned short Pl[4][2][16*PSTR];   // 17408 B  (total 50176 B)

  // 512 blocks; cluster one bh's 16 blocks onto one XCD (flat % 8 = XCD)
  const int flat = blockIdx.x;
  const int bh  = (flat & 7) * 4 + ((flat >> 3) & 3);
  const int qz  = flat >> 5;             // 0..15
  const int qb  = qz & 7, z = qz >> 3;   // 8 query blocks x 2 splits
  const int t = threadIdx.x;
  const int lane = t & 63, w = t >> 6, quad = lane >> 4, lid = lane & 15;
  const int q0 = qb * 256 + w * 64;
  const int kbeg = z * (SEQ/NSPLIT);
  const int r8 = lane >> 3, c8 = (lane & 7) * 8;
  _Float16* Op = Op0 + (size_t)z * BH * SEQ * DIM_HEAD;
  float* lp = lpart + (size_t)z * BH * SEQ;

  // Q fragments (B-frag): lane lid = query row, contiguous 2KB per load
  short8 qf[4][2];
#pragma unroll
  for (int st = 0; st < 4; st++)
#pragma unroll
    for (int kst = 0; kst < 2; kst++)
      qf[st][kst] = *(const short8*)(Q +
        ((size_t)(bh*SEQ + q0 + st*16 + lid))*DIM_HEAD + kst*32 + quad*8);

  float4v o[4][4];
#pragma unroll
  for (int st = 0; st < 4; st++)
#pragma unroll
    for (int i = 0; i < 4; i++) o[st][i] = (float4v)0.0f;
  float ps[4] = {0.0f, 0.0f, 0.0f, 0.0f};

  // prologue: stage iter-0 tiles into buf 0 (wave w stages rows w*16..w*16+15)
#pragma unroll
  for (int p = 0; p < 2; p++) {
    int row = w*16 + p*8 + r8;
    gld16(K + ((size_t)(bh*SEQ + kbeg + row))*DIM_HEAD + c8, &Kl[0][(w*16 + p*8)*64]);
    gld16(VT + ((size_t)(bh*(SEQ/64) + (kbeg >> 6))*DIM_HEAD + row)*64 + c8,
          &Vl[0][(w*16 + p*8)*64]);
  }

  const int NIT = (SEQ/NSPLIT)/64;   // 16
  for (int it = 0; it < NIT; it++) {
    const int cur = it & 1;
    __syncthreads();   // drains DMA for cur; all waves done reading buf cur^1
    if (it + 1 < NIT) {
      int kb = kbeg + (it+1)*64;
#pragma unroll
      for (int p = 0; p < 2; p++) {
        int row = w*16 + p*8 + r8;
        gld16(K + ((size_t)(bh*SEQ + kb + row))*DIM_HEAD + c8, &Kl[cur^1][(w*16 + p*8)*64]);
        gld16(VT + ((size_t)(bh*(SEQ/64) + (kb >> 6))*DIM_HEAD + row)*64 + c8,
              &Vl[cur^1][(w*16 + p*8)*64]);
      }
    }
    // fragments from shared LDS tiles (m97-pattern b128 reads)
    short8 kf[2][4], vf[2][4];
#pragma unroll
    for (int kst = 0; kst < 2; kst++)
#pragma unroll
      for (int mb = 0; mb < 4; mb++)
        kf[kst][mb] = *(const short8*)&Kl[cur][(mb*16 + lid)*64 + kst*32 + quad*8];
#pragma unroll
    for (int kst = 0; kst < 2; kst++)
#pragma unroll
      for (int i = 0; i < 4; i++)
        vf[kst][i] = *(const short8*)&Vl[cur][(i*16 + lid)*64 + kst*32 + quad*8];

#pragma unroll
    for (int st = 0; st < 4; st++) {
      float4v s[4];
#pragma unroll
      for (int mb = 0; mb < 4; mb++) s[mb] = (float4v)0.0f;
#pragma unroll
      for (int kst = 0; kst < 2; kst++)
#pragma unroll
        for (int mb = 0; mb < 4; mb++)
          s[mb] = __builtin_amdgcn_mfma_f32_16x16x32_bf16(kf[kst][mb], qf[st][kst], s[mb], 0, 0, 0);

      unsigned short* Ptw = &Pl[w][st & 1][0];
#pragma unroll
      for (int mb = 0; mb < 4; mb++) {
        float e0 = __expf(s[mb][0]);
        float e1 = __expf(s[mb][1]);
        float e2 = __expf(s[mb][2]);
        float e3 = __expf(s[mb][3]);
        ps[st] += (e0 + e1) + (e2 + e3);
        uint2 pk; pk.x = pk2bf(e0, e1); pk.y = pk2bf(e2, e3);
        *(uint2*)&Ptw[lid*PSTR + mb*16 + quad*4] = pk;
      }
      short8 pf0 = *(const short8*)&Ptw[lid*PSTR + quad*8];
      short8 pf1 = *(const short8*)&Ptw[lid*PSTR + 32 + quad*8];
#pragma unroll
      for (int i = 0; i < 4; i++) {
        o[st][i] = __builtin_amdgcn_mfma_f32_16x16x32_bf16(vf[0][i], pf0, o[st][i], 0, 0, 0);
        o[st][i] = __builtin_amdgcn_mfma_f32_16x16x32_bf16(vf[1][i], pf1, o[st][i], 0, 0, 0);
      }
    }
  }

  // epilogue: l partial (sum over quads) + fp16 O^T partial
#pragma unroll
  for (int st = 0; st < 4; st++) {
    float v = ps[st];
    v += __shfl_xor(v, 16); v += __shfl_xor(v, 32);
    int q = q0 + st*16 + lid;
    if (quad == 0) lp[(size_t)bh*SEQ + q] = v;
#pragma unroll
    for (int i = 0; i < 4; i++) {
      half4v hv;
#pragma unroll
      for (int r = 0; r < 4; r++) hv[r] = (_Float16)o[st][i][r];
      *(half4v*)(Op + ((size_t)bh*SEQ + q)*64 + i*16 + quad*4) = hv;
    }
  }
}

// ---- combine splits: Ob = bf16(Sum O_z / Sum l_z), layout [b,q,h,d] --------
__global__ __launch_bounds__(256) void norm_kernel(const _Float16* __restrict__ Op,
    const float* __restrict__ lpart, unsigned short* __restrict__ Ob) {
  int g = blockIdx.x * 256 + threadIdx.x;
  int d4 = g & 15, h = (g >> 4) & 15, q = (g >> 8) & (SEQ - 1), b = g >> 19;
  int bh = b * NHEAD + h;
  size_t obase = ((size_t)bh * SEQ + q) * 64 + d4 * 4;
  const size_t zstride = (size_t)BH * SEQ * DIM_HEAD;
  float f0 = 0.f, f1 = 0.f, f2 = 0.f, f3 = 0.f, l = 0.f;
#pragma unroll
  for (int zz = 0; zz < NSPLIT; zz++) {
    half4v a = *(const half4v*)(Op + (size_t)zz * zstride + obase);
    f0 += (float)a[0]; f1 += (float)a[1]; f2 += (float)a[2]; f3 += (float)a[3];
    l += lpart[(size_t)zz * BH * SEQ + (size_t)bh * SEQ + q];
  }
  float inv = 1.0f / l;
  f0 *= inv; f1 *= inv; f2 *= inv; f3 *= inv;
  uint2 pk; pk.x = pk2bf(f0, f1); pk.y = pk2bf(f2, f3);
  *(uint2*)&Ob[(((size_t)(b*SEQ + q))*NHEAD + h)*64 + d4*4] = pk;
}

extern "C" void kernel_launch(void* const* d_in, const int* in_sizes, int n_in,
                              void* d_out, int out_size, void* d_ws, size_t ws_size,
                              hipStream_t stream) {
  const float* query = (const float*)d_in[0];
  const float* key_  = (const float*)d_in[1];
  const float* value = (const float*)d_in[2];
  const float* Wq = (const float*)d_in[3];
  const float* Wk = (const float*)d_in[4];
  const float* Wv = (const float*)d_in[5];
  const float* Wo = (const float*)d_in[6];
  const float* bo = (const float*)d_in[7];
  float* out = (float*)d_out;

  char* ws = (char*)d_ws;
  unsigned short* WT0 = (unsigned short*)(ws);                  // 4 x 2MB
  unsigned short* Xbf = (unsigned short*)(ws + (8ll  << 20));   // 3 x 8MB
  unsigned short* VT  = (unsigned short*)(ws + (8ll  << 20));   // reuse Xbf[q]
  unsigned short* Ob  = (unsigned short*)(ws + (16ll << 20));   // reuse Xbf[k]
  unsigned short* Qb  = (unsigned short*)(ws + (32ll << 20));   // head-major
  unsigned short* Kb  = (unsigned short*)(ws + (40ll << 20));
  unsigned short* Vb  = (unsigned short*)(ws + (48ll << 20));
  _Float16*       Op  = (_Float16*)     (ws + (56ll << 20));    // 2 x 8MB partials
  float*          lp  = (float*)        (ws + (88ll << 20));    // 512KB

  dim3 tb(256);
  dim3 tg(32, 32, 4);
  hipLaunchKernelGGL(wtrans_kernel, tg, tb, 0, stream, Wq, Wk, Wv, Wo, WT0);

  dim3 cg(MK / (256*8), 3);
  hipLaunchKernelGGL(cast_kernel, cg, tb, 0, stream, query, key_, value, Xbf);

  dim3 pg(MROWS/128, D_MODEL/128, 3);   // 768 blocks
  hipLaunchKernelGGL(proj_kernel, pg, tb, 0, stream, Xbf, WT0, Qb);

  dim3 vg(BH, SEQ/64);
  hipLaunchKernelGGL(vtrans_kernel, vg, tb, 0, stream, Vb, VT);

  dim3 fg(512);                         // LDS-shared dbuf flash, split-K x2
  hipLaunchKernelGGL(flash_kernel, fg, tb, 0, stream, Qb, Kb, VT, Op, lp);

  dim3 ng((MROWS * NHEAD * DIM_HEAD / 4) / 256);   // 2048 blocks
  hipLaunchKernelGGL(norm_kernel, ng, tb, 0, stream, Op, lp, Ob);

  dim3 og(MROWS/64, D_MODEL/128);       // 512 blocks
  hipLaunchKernelGGL(outproj_kernel, og, tb, 0, stream, Ob, WT0 + (3ll << 20), bo, out);
}